// Round 9
// baseline (134.971 us; speedup 1.0000x reference)
//
#include <hip/hip_runtime.h>
#include <stdint.h>

#define TDIM 4096   // tokens = 2*2048
#define KDIM 4096   // IN_F
#define NDIM 4096   // OUT_F
#define RANK 128
#define NG   32

typedef __attribute__((ext_vector_type(4))) int   i32x4;
typedef __attribute__((ext_vector_type(4))) float f32x4;
typedef __attribute__((ext_vector_type(8))) short short8;
typedef __attribute__((ext_vector_type(8))) unsigned short u16x8;
typedef __attribute__((ext_vector_type(8))) char c8;

__device__ inline unsigned short f2bf(float f) {   // f32 -> bf16 RNE
    union { float f; unsigned u; } v; v.f = f;
    const unsigned r = v.u + 0x7FFF + ((v.u >> 16) & 1);
    return (unsigned short)(r >> 16);
}
__device__ inline float bf2f(unsigned short h) {
    union { unsigned u; float f; } v; v.u = (unsigned)h << 16;
    return v.f;
}

// ---------------------------------------------------------------------------
// Kernel 1: per-token activation quantization (unchanged).
// ---------------------------------------------------------------------------
__global__ __launch_bounds__(256) void quant_x_kernel(
    const float* __restrict__ x, int8_t* __restrict__ xq,
    float* __restrict__ scale_x)
{
    const int row = blockIdx.x;
    const float4* xr = (const float4*)(x + (size_t)row * KDIM);
    __shared__ float4 buf[1024];
    __shared__ float wred[4];

    float m = 0.f;
    #pragma unroll
    for (int j = 0; j < 4; ++j) {
        const float4 v = xr[threadIdx.x + j * 256];
        buf[threadIdx.x + j * 256] = v;
        m = fmaxf(m, fmaxf(fmaxf(fabsf(v.x), fabsf(v.y)),
                           fmaxf(fabsf(v.z), fabsf(v.w))));
    }
    #pragma unroll
    for (int off = 32; off > 0; off >>= 1)
        m = fmaxf(m, __shfl_xor(m, off, 64));
    if ((threadIdx.x & 63) == 0) wred[threadIdx.x >> 6] = m;
    __syncthreads();
    const float mt = fmaxf(fmaxf(wred[0], wred[1]), fmaxf(wred[2], wred[3]));
    const float sx = mt / 127.0f;
    if (threadIdx.x == 0) scale_x[row] = sx;

    char4* xo = (char4*)(xq + (size_t)row * KDIM);
    #pragma unroll
    for (int j = 0; j < 4; ++j) {
        const float4 v = buf[threadIdx.x + j * 256];
        char4 q;
        q.x = (char)fminf(fmaxf(rintf(v.x / sx), -128.f), 127.f);
        q.y = (char)fminf(fmaxf(rintf(v.y / sx), -128.f), 127.f);
        q.z = (char)fminf(fmaxf(rintf(v.z / sx), -128.f), 127.f);
        q.w = (char)fminf(fmaxf(rintf(v.w / sx), -128.f), 127.f);
        xo[threadIdx.x + j * 256] = q;
    }
}

// ---------------------------------------------------------------------------
// Kernel 1b: convert svd factors to bf16 (unchanged).
// ---------------------------------------------------------------------------
__global__ __launch_bounds__(256) void conv_svd_kernel(
    const float* __restrict__ svd_up, const float* __restrict__ svd_down,
    unsigned short* __restrict__ upb, unsigned short* __restrict__ dnt)
{
    const int b = blockIdx.x;
    if (b < 256) {
        const int t = b * 256 + threadIdx.x;
        const int i  = t >> 4;
        const int k0 = (t & 15) * 8;
        u16x8 v;
        #pragma unroll
        for (int j = 0; j < 8; ++j)
            v[j] = f2bf(svd_down[(size_t)(k0 + j) * KDIM + i]);
        *(u16x8*)(dnt + (size_t)i * RANK + k0) = v;
    } else {
        const int t = (b - 256) * 256 + threadIdx.x;
        const float4* src = (const float4*)svd_up + (size_t)t * 4;
        #pragma unroll
        for (int h = 0; h < 2; ++h) {
            const float4 a = src[h * 2], c = src[h * 2 + 1];
            u16x8 v;
            v[0] = f2bf(a.x); v[1] = f2bf(a.y); v[2] = f2bf(a.z); v[3] = f2bf(a.w);
            v[4] = f2bf(c.x); v[5] = f2bf(c.y); v[6] = f2bf(c.z); v[7] = f2bf(c.w);
            *(u16x8*)(upb + (size_t)t * 16 + h * 8) = v;
        }
    }
}

// ---------------------------------------------------------------------------
// Kernel 2 (FUSED, unchanged from R7): dequant + SVD corr + row max +
// quantize -> wq, scale_w. bf16 wf staged in LDS; no HBM scratch.
// ---------------------------------------------------------------------------
__global__ __launch_bounds__(512) void fused_w_kernel(
    const int* __restrict__ Wq, const float* __restrict__ scale,
    const float* __restrict__ zp,
    const unsigned short* __restrict__ upb,   // [4096][128] bf16
    const unsigned short* __restrict__ dnt,   // [4096][128] bf16 (down^T)
    int8_t* __restrict__ wq, float* __restrict__ scale_w)
{
    __shared__ unsigned short wfls[16 * 4096];   // 128 KB
    __shared__ float red[16][8];
    __shared__ float swls[16];

    const int tid  = threadIdx.x;
    const int lane = tid & 63, wid = tid >> 6;   // 8 waves
    const int l15  = lane & 15, l16 = lane >> 4;
    const int o0   = blockIdx.x * 16;

    short8 af[4];
    #pragma unroll
    for (int kk = 0; kk < 4; ++kk)
        af[kk] = *(const short8*)(upb + (size_t)(o0 + l15) * RANK + kk * 32 + l16 * 8);

    const int swz = l16 << 4;
    unsigned umax[4] = {0u, 0u, 0u, 0u};

    for (int c = 0; c < 4; ++c) {
        const int cb = wid * 512 + c * 128;
        const int g  = cb >> 7;

        f32x4 acc[8];
        #pragma unroll
        for (int t = 0; t < 8; ++t) acc[t] = (f32x4){0.f, 0.f, 0.f, 0.f};
        #pragma unroll
        for (int t = 0; t < 8; ++t)
            #pragma unroll
            for (int kk = 0; kk < 4; ++kk) {
                const short8 bfr = *(const short8*)(dnt +
                    (size_t)(cb + t * 16 + l15) * RANK + kk * 32 + l16 * 8);
                acc[t] = __builtin_amdgcn_mfma_f32_16x16x32_bf16(
                             af[kk], bfr, acc[t], 0, 0, 0);
            }

        float s[4], z[4];
        #pragma unroll
        for (int j = 0; j < 4; ++j) {
            const int row = o0 + l16 * 4 + j;
            s[j] = scale[row * NG + g];
            z[j] = zp[row * NG + g];
        }

        #pragma unroll
        for (int t = 0; t < 8; ++t) {
            const int col = cb + t * 16 + l15;
            #pragma unroll
            for (int j = 0; j < 4; ++j) {
                const int r = l16 * 4 + j;
                const float q  = (float)Wq[(size_t)(o0 + r) * KDIM + col];
                const float wf = (q - z[j]) * s[j] + acc[t][j];
                const unsigned short h = f2bf(wf);
                wfls[r * 4096 + (col ^ swz)] = h;
                const unsigned a = h & 0x7FFFu;
                umax[j] = (a > umax[j]) ? a : umax[j];
            }
        }
    }

    #pragma unroll
    for (int j = 0; j < 4; ++j) {
        unsigned v = umax[j];
        v = max(v, (unsigned)__shfl_xor((int)v, 1, 64));
        v = max(v, (unsigned)__shfl_xor((int)v, 2, 64));
        v = max(v, (unsigned)__shfl_xor((int)v, 4, 64));
        v = max(v, (unsigned)__shfl_xor((int)v, 8, 64));
        if (l15 == 0) red[l16 * 4 + j][wid] = bf2f((unsigned short)v);
    }
    __syncthreads();
    if (tid < 16) {
        float m = 0.f;
        #pragma unroll
        for (int w = 0; w < 8; ++w) m = fmaxf(m, red[tid][w]);
        const float sw = m / 127.0f;
        swls[tid] = sw;
        scale_w[o0 + tid] = sw;
    }
    __syncthreads();

    const int r  = tid >> 5;
    const int ml = tid & 31;
    const float sw = swls[r];
    const int rsw = ((r >> 2) & 3) << 4;
    int8_t* wrow = wq + (size_t)(o0 + r) * KDIM;
    #pragma unroll
    for (int k = 0; k < 16; ++k) {
        const int c0 = k * 256 + ml * 8;
        const u16x8 h = *(const u16x8*)(wfls + r * 4096 + (c0 ^ rsw));
        c8 qv;
        #pragma unroll
        for (int e = 0; e < 8; ++e) {
            float f = bf2f((unsigned short)h[e]);
            qv[e] = (char)fminf(fmaxf(rintf(f / sw), -128.f), 127.f);
        }
        *(c8*)(wrow + c0) = qv;
    }
}

// ---------------------------------------------------------------------------
// Kernel 4: int8 GEMM 256x256, BK=64, 4-deep staging — R8: ONE barrier per
// K-tile, ds_reads interleaved into the MFMA stream.
// R5-R7 counters showed MfmaUtil pinned at 38% with conflicts=0: the 4-
// barriers-per-tile structure put all ds_reads in one rendezvous window and
// all MFMA in another, so the LDS pipe (~1150 cyc/tile) and the MFMA pipe
// (~1150 cyc/tile) strictly alternated (2700 cyc/tile measured). This
// structure lets them overlap: reads for A-half1 are issued between MFMA
// rows, and 2 waves/SIMD drift within the single barrier interval.
// Choreography (R5-proven semantics, unchanged): all waves rendezvous once
// per tile; tile t reads buf[t&3], stages tile t+3 into buf[(t+3)&3] (last
// read at t-1, behind the barrier); per-wave vmcnt(8) + barrier publishes
// tile t+1 (12 outstanding -> drains the oldest 4). Tail dummies (u=63)
// rotate through consumed buffers; vmcnt(0) after the loop.
// ---------------------------------------------------------------------------
__global__ __launch_bounds__(512, 2) void gemm_i8_kernel(
    const int8_t* __restrict__ Aq,   // [T][K]
    const int8_t* __restrict__ Bq,   // [N][K]
    const float* __restrict__ scale_x, const float* __restrict__ scale_w,
    const float* __restrict__ bias, float* __restrict__ out)
{
    __shared__ __align__(16) int8_t lds[131072];
    // A: buf*16384 + h*8192 (128 rows x 64B), bufs 0..3 in [0,64K)
    // B: 65536 + buf*16384 + h*8192             in [64K,128K)

    const int tid  = threadIdx.x;
    const int lane = tid & 63;
    const int wid  = tid >> 6;
    const int wmp  = wid >> 2;
    const int wnp  = wid & 3;
    const int l15  = lane & 15, l16 = lane >> 4;

    const int swz  = (blockIdx.x & 7) * 32 + (blockIdx.x >> 3);
    const int row0 = (swz >> 4) * 256;
    const int col0 = (swz & 15) * 256;

    const int srow = wid * 16 + (lane >> 2);
    const int scol = ((lane & 3) ^ ((lane >> 3) & 3)) * 16;
    const int8_t* const A0 = Aq + (size_t)(row0 + srow) * KDIM + scol;
    const int8_t* const B0 = Bq + (size_t)(col0 + srow) * KDIM + scol;
    int8_t* const ldsw = lds + wid * 1024;

#define STAGE_A(db, h, kt) \
    __builtin_amdgcn_global_load_lds( \
        (const __attribute__((address_space(1))) void*)(A0 + (size_t)(h) * 128 * KDIM + (kt) * 64), \
        (__attribute__((address_space(3))) void*)(ldsw + (db) * 16384 + (h) * 8192), 16, 0, 0)
#define STAGE_B(db, h, kt) \
    __builtin_amdgcn_global_load_lds( \
        (const __attribute__((address_space(1))) void*)(B0 + (size_t)(h) * 128 * KDIM + (kt) * 64), \
        (__attribute__((address_space(3))) void*)(ldsw + 65536 + (db) * 16384 + (h) * 8192), 16, 0, 0)

    const int rslot = (l16 ^ ((lane >> 1) & 3)) * 16;
    const int aoff = wmp * 8192 + l15 * 64 + rslot;
    const int boff = (wnp >> 1) * 8192 + (wnp & 1) * 4096 + l15 * 64 + rslot;

    i32x4 Ar[8], Br[4];
    i32x4 acc[8][4];
    #pragma unroll
    for (int m = 0; m < 8; ++m)
        #pragma unroll
        for (int n = 0; n < 4; ++n) acc[m][n] = (i32x4){0, 0, 0, 0};

#define LDA4(db, qm) { const int8_t* p = lds + (db) * 16384 + aoff + (qm) * 4096; \
    Ar[(qm) * 4 + 0] = *(const i32x4*)(p);        Ar[(qm) * 4 + 1] = *(const i32x4*)(p + 1024); \
    Ar[(qm) * 4 + 2] = *(const i32x4*)(p + 2048); Ar[(qm) * 4 + 3] = *(const i32x4*)(p + 3072); }
#define LDB2(db, qn) { const int8_t* p = lds + 65536 + (db) * 16384 + boff + (qn) * 2048; \
    Br[(qn) * 2 + 0] = *(const i32x4*)(p);        Br[(qn) * 2 + 1] = *(const i32x4*)(p + 1024); }
#define M1(i, j) acc[i][j] = __builtin_amdgcn_mfma_i32_16x16x64_i8(Ar[i], Br[j], acc[i][j], 0, 0, 0)
#define MROW(i) { M1(i, 0); M1(i, 1); M1(i, 2); M1(i, 3); }

#define FENCE asm volatile("" ::: "memory")
#define BAR   __builtin_amdgcn_s_barrier()
#define VMCNT8 asm volatile("s_waitcnt vmcnt(8)" ::: "memory")
#define VMCNT0 asm volatile("s_waitcnt vmcnt(0)" ::: "memory")
#define PRIO1 __builtin_amdgcn_s_setprio(1)
#define PRIO0 __builtin_amdgcn_s_setprio(0)

    // One barrier interval per K-tile:
    //   reads(B, A-half0) -> stages(t+3) -> MFMA rows 0-1 -> read A-half1
    //   (latency hidden under rows 2-3) -> MFMA rows 2-7 -> vmcnt(8) -> BAR
#define TILE(rb, sb, u) { \
    LDB2(rb, 0); LDB2(rb, 1); LDA4(rb, 0); \
    FENCE; \
    STAGE_A(sb, 0, u); STAGE_A(sb, 1, u); STAGE_B(sb, 0, u); STAGE_B(sb, 1, u); \
    FENCE; \
    PRIO1; \
    MROW(0); MROW(1); \
    LDA4(rb, 1); \
    MROW(2); MROW(3); MROW(4); MROW(5); MROW(6); MROW(7); \
    PRIO0; \
    VMCNT8; BAR; }

    // prologue: stage tiles 0,1,2 fully; vmcnt(8) -> tile 0 complete.
    STAGE_A(0, 0, 0); STAGE_A(0, 1, 0); STAGE_B(0, 0, 0); STAGE_B(0, 1, 0);
    STAGE_A(1, 0, 1); STAGE_A(1, 1, 1); STAGE_B(1, 0, 1); STAGE_B(1, 1, 1);
    STAGE_A(2, 0, 2); STAGE_A(2, 1, 2); STAGE_B(2, 0, 2); STAGE_B(2, 1, 2);
    VMCNT8;
    BAR;

    for (int j = 0; j < 16; ++j) {
        const int t0 = 4 * j;
        const int u1 = (t0 + 4 > 63) ? 63 : t0 + 4;
        const int u2 = (t0 + 5 > 63) ? 63 : t0 + 5;
        const int u3 = (t0 + 6 > 63) ? 63 : t0 + 6;
        TILE(0, 3, t0 + 3);
        TILE(1, 0, u1);
        TILE(2, 1, u2);
        TILE(3, 2, u3);
    }
    VMCNT0;   // drain tail dummies before kernel end

    // epilogue: C/D layout col = lane&15, row = (lane>>4)*4 + reg
    const int orow0 = row0 + wmp * 128;
    const int ocol0 = col0 + wnp * 64;
    #pragma unroll
    for (int fn = 0; fn < 4; ++fn) {
        const int col = ocol0 + fn * 16 + l15;
        const float sw = scale_w[col];
        const float bv = bias[col];
        #pragma unroll
        for (int fm = 0; fm < 8; ++fm) {
            #pragma unroll
            for (int j = 0; j < 4; ++j) {
                const int row = orow0 + fm * 16 + l16 * 4 + j;
                out[(size_t)row * NDIM + col] =
                    (float)acc[fm][fn][j] * scale_x[row] * sw + bv;
            }
        }
    }
#undef STAGE_A
#undef STAGE_B
#undef LDA4
#undef LDB2
#undef M1
#undef MROW
#undef TILE
#undef FENCE
#undef BAR
#undef VMCNT8
#undef VMCNT0
#undef PRIO1
#undef PRIO0
}

// ---------------------------------------------------------------------------
extern "C" void kernel_launch(void* const* d_in, const int* in_sizes, int n_in,
                              void* d_out, int out_size, void* d_ws, size_t ws_size,
                              hipStream_t stream)
{
    const float* x        = (const float*)d_in[0];
    const int*   Wq       = (const int*)d_in[1];
    const float* scale    = (const float*)d_in[2];
    const float* zp       = (const float*)d_in[3];
    const float* svd_up   = (const float*)d_in[4];
    const float* svd_down = (const float*)d_in[5];
    const float* bias     = (const float*)d_in[6];
    float* out = (float*)d_out;

    // ws: xq 16MB | wq 16MB | scale_x 16KB | scale_w 16KB | upb 1MB | dnt 1MB
    int8_t* xq = (int8_t*)d_ws;
    int8_t* wq = (int8_t*)d_ws + ((size_t)16 << 20);
    float* scale_x = (float*)((char*)d_ws + ((size_t)32 << 20));
    float* scale_w = scale_x + TDIM;
    unsigned short* upb = (unsigned short*)(scale_w + NDIM);
    unsigned short* dnt = upb + (size_t)NDIM * RANK;

    quant_x_kernel<<<TDIM, 256, 0, stream>>>(x, xq, scale_x);
    conv_svd_kernel<<<384, 256, 0, stream>>>(svd_up, svd_down, upb, dnt);
    fused_w_kernel<<<NDIM / 16, 512, 0, stream>>>(Wq, scale, zp, upb, dnt,
                                                  wq, scale_w);
    gemm_i8_kernel<<<(TDIM / 256) * (NDIM / 256), 512, 0, stream>>>(
        xq, wq, scale_x, scale_w, bias, out);
}

// Round 10
// 133.738 us; speedup vs baseline: 1.0092x; 1.0092x over previous
//
#include <hip/hip_runtime.h>
#include <stdint.h>

#define TDIM 4096   // tokens = 2*2048
#define KDIM 4096   // IN_F
#define NDIM 4096   // OUT_F
#define RANK 128
#define NG   32

typedef __attribute__((ext_vector_type(4))) int   i32x4;
typedef __attribute__((ext_vector_type(4))) float f32x4;
typedef __attribute__((ext_vector_type(8))) short short8;
typedef __attribute__((ext_vector_type(8))) unsigned short u16x8;
typedef __attribute__((ext_vector_type(8))) char c8;

__device__ inline unsigned short f2bf(float f) {   // f32 -> bf16 RNE
    union { float f; unsigned u; } v; v.f = f;
    const unsigned r = v.u + 0x7FFF + ((v.u >> 16) & 1);
    return (unsigned short)(r >> 16);
}
__device__ inline float bf2f(unsigned short h) {
    union { unsigned u; float f; } v; v.u = (unsigned)h << 16;
    return v.f;
}

// ---------------------------------------------------------------------------
// Kernel 1 (merged): blocks 0..4095 = per-token activation quant;
// blocks 4096..4479 = svd bf16 conversion. Saves one launch drain.
// ---------------------------------------------------------------------------
__global__ __launch_bounds__(256) void prep_kernel(
    const float* __restrict__ x, int8_t* __restrict__ xq,
    float* __restrict__ scale_x,
    const float* __restrict__ svd_up, const float* __restrict__ svd_down,
    unsigned short* __restrict__ upb, unsigned short* __restrict__ dnt)
{
    if (blockIdx.x < 4096) {
        const int row = blockIdx.x;
        const float4* xr = (const float4*)(x + (size_t)row * KDIM);
        __shared__ float4 buf[1024];
        __shared__ float wred[4];

        float m = 0.f;
        #pragma unroll
        for (int j = 0; j < 4; ++j) {
            const float4 v = xr[threadIdx.x + j * 256];
            buf[threadIdx.x + j * 256] = v;
            m = fmaxf(m, fmaxf(fmaxf(fabsf(v.x), fabsf(v.y)),
                               fmaxf(fabsf(v.z), fabsf(v.w))));
        }
        #pragma unroll
        for (int off = 32; off > 0; off >>= 1)
            m = fmaxf(m, __shfl_xor(m, off, 64));
        if ((threadIdx.x & 63) == 0) wred[threadIdx.x >> 6] = m;
        __syncthreads();
        const float mt = fmaxf(fmaxf(wred[0], wred[1]), fmaxf(wred[2], wred[3]));
        const float sx = mt / 127.0f;
        if (threadIdx.x == 0) scale_x[row] = sx;

        char4* xo = (char4*)(xq + (size_t)row * KDIM);
        #pragma unroll
        for (int j = 0; j < 4; ++j) {
            const float4 v = buf[threadIdx.x + j * 256];
            char4 q;
            q.x = (char)fminf(fmaxf(rintf(v.x / sx), -128.f), 127.f);
            q.y = (char)fminf(fmaxf(rintf(v.y / sx), -128.f), 127.f);
            q.z = (char)fminf(fmaxf(rintf(v.z / sx), -128.f), 127.f);
            q.w = (char)fminf(fmaxf(rintf(v.w / sx), -128.f), 127.f);
            xo[threadIdx.x + j * 256] = q;
        }
    } else {
        const int b = blockIdx.x - 4096;
        if (b < 256) {
            const int t = b * 256 + threadIdx.x;
            const int i  = t >> 4;
            const int k0 = (t & 15) * 8;
            u16x8 v;
            #pragma unroll
            for (int j = 0; j < 8; ++j)
                v[j] = f2bf(svd_down[(size_t)(k0 + j) * KDIM + i]);
            *(u16x8*)(dnt + (size_t)i * RANK + k0) = v;
        } else {
            const int t = (b - 256) * 256 + threadIdx.x;
            const float4* src = (const float4*)svd_up + (size_t)t * 4;
            #pragma unroll
            for (int h = 0; h < 2; ++h) {
                const float4 a = src[h * 2], c = src[h * 2 + 1];
                u16x8 v;
                v[0] = f2bf(a.x); v[1] = f2bf(a.y); v[2] = f2bf(a.z); v[3] = f2bf(a.w);
                v[4] = f2bf(c.x); v[5] = f2bf(c.y); v[6] = f2bf(c.z); v[7] = f2bf(c.w);
                *(u16x8*)(upb + (size_t)t * 16 + h * 8) = v;
            }
        }
    }
}

// ---------------------------------------------------------------------------
// Kernel 2 (FUSED, unchanged from R7/R8): dequant + SVD corr + row max +
// quantize -> wq, scale_w. bf16 wf staged in LDS; no HBM scratch.
// ---------------------------------------------------------------------------
__global__ __launch_bounds__(512) void fused_w_kernel(
    const int* __restrict__ Wq, const float* __restrict__ scale,
    const float* __restrict__ zp,
    const unsigned short* __restrict__ upb,   // [4096][128] bf16
    const unsigned short* __restrict__ dnt,   // [4096][128] bf16 (down^T)
    int8_t* __restrict__ wq, float* __restrict__ scale_w)
{
    __shared__ unsigned short wfls[16 * 4096];   // 128 KB
    __shared__ float red[16][8];
    __shared__ float swls[16];

    const int tid  = threadIdx.x;
    const int lane = tid & 63, wid = tid >> 6;   // 8 waves
    const int l15  = lane & 15, l16 = lane >> 4;
    const int o0   = blockIdx.x * 16;

    short8 af[4];
    #pragma unroll
    for (int kk = 0; kk < 4; ++kk)
        af[kk] = *(const short8*)(upb + (size_t)(o0 + l15) * RANK + kk * 32 + l16 * 8);

    const int swz = l16 << 4;
    unsigned umax[4] = {0u, 0u, 0u, 0u};

    for (int c = 0; c < 4; ++c) {
        const int cb = wid * 512 + c * 128;
        const int g  = cb >> 7;

        f32x4 acc[8];
        #pragma unroll
        for (int t = 0; t < 8; ++t) acc[t] = (f32x4){0.f, 0.f, 0.f, 0.f};
        #pragma unroll
        for (int t = 0; t < 8; ++t)
            #pragma unroll
            for (int kk = 0; kk < 4; ++kk) {
                const short8 bfr = *(const short8*)(dnt +
                    (size_t)(cb + t * 16 + l15) * RANK + kk * 32 + l16 * 8);
                acc[t] = __builtin_amdgcn_mfma_f32_16x16x32_bf16(
                             af[kk], bfr, acc[t], 0, 0, 0);
            }

        float s[4], z[4];
        #pragma unroll
        for (int j = 0; j < 4; ++j) {
            const int row = o0 + l16 * 4 + j;
            s[j] = scale[row * NG + g];
            z[j] = zp[row * NG + g];
        }

        #pragma unroll
        for (int t = 0; t < 8; ++t) {
            const int col = cb + t * 16 + l15;
            #pragma unroll
            for (int j = 0; j < 4; ++j) {
                const int r = l16 * 4 + j;
                const float q  = (float)Wq[(size_t)(o0 + r) * KDIM + col];
                const float wf = (q - z[j]) * s[j] + acc[t][j];
                const unsigned short h = f2bf(wf);
                wfls[r * 4096 + (col ^ swz)] = h;
                const unsigned a = h & 0x7FFFu;
                umax[j] = (a > umax[j]) ? a : umax[j];
            }
        }
    }

    #pragma unroll
    for (int j = 0; j < 4; ++j) {
        unsigned v = umax[j];
        v = max(v, (unsigned)__shfl_xor((int)v, 1, 64));
        v = max(v, (unsigned)__shfl_xor((int)v, 2, 64));
        v = max(v, (unsigned)__shfl_xor((int)v, 4, 64));
        v = max(v, (unsigned)__shfl_xor((int)v, 8, 64));
        if (l15 == 0) red[l16 * 4 + j][wid] = bf2f((unsigned short)v);
    }
    __syncthreads();
    if (tid < 16) {
        float m = 0.f;
        #pragma unroll
        for (int w = 0; w < 8; ++w) m = fmaxf(m, red[tid][w]);
        const float sw = m / 127.0f;
        swls[tid] = sw;
        scale_w[o0 + tid] = sw;
    }
    __syncthreads();

    const int r  = tid >> 5;
    const int ml = tid & 31;
    const float sw = swls[r];
    const int rsw = ((r >> 2) & 3) << 4;
    int8_t* wrow = wq + (size_t)(o0 + r) * KDIM;
    #pragma unroll
    for (int k = 0; k < 16; ++k) {
        const int c0 = k * 256 + ml * 8;
        const u16x8 h = *(const u16x8*)(wfls + r * 4096 + (c0 ^ rsw));
        c8 qv;
        #pragma unroll
        for (int e = 0; e < 8; ++e) {
            float f = bf2f((unsigned short)h[e]);
            qv[e] = (char)fminf(fmaxf(rintf(f / sw), -128.f), 127.f);
        }
        *(c8*)(wrow + c0) = qv;
    }
}

// ---------------------------------------------------------------------------
// Kernel 4: int8 GEMM 256x256, BK=64, 4-deep LDS rotation — R9: register
// double-buffered cross-tile prefetch. All prior schedules (R5-R8, all
// ~2700cyc/tile, MfmaUtil 38-40%) shared one flaw: tile t's ds_reads are
// issued AND lgkm-drained inside the interval that consumes them -> every
// tile starts with an exposed read batch, and at 1 block/CU (grid=256,
// forced by the traffic-optimal 256² tiling, R6) nothing fills the hole.
// Now: tile t+1's B + A-half0 are read into a SHADOW register set after the
// mid-interval vmcnt(8)+BAR (which publishes buf t+1), interleaved under
// tile t's rows 4-7 MFMAs; A-half1 is read JIT under rows 0-3. The MFMA
// stream crosses tile boundaries without waiting on lgkm.
// Choreography (distance-3 rotation, R5-proven):
//  - interval t: stage tile t+3 -> buf (t+3)&3. That buf's last ds_reads
//    (tile t-1) finished in interval t-2's tail / t-1's JIT read, sealed by
//    >=1 barrier before interval t. Safe.
//  - vmcnt(8) mid-interval t: 12 outstanding (stages t+1,t+2,t+3) -> drains
//    the 4 oldest = tile t+1 complete; BAR publishes it; tail reads follow.
//  - tail: kt clamped to 63 (dummy re-stages, rotation bufs, never consumed);
//    interval 63's tail-reads hit valid dummy LDS, results unused.
//  - vmcnt(0) before epilogue.
// ---------------------------------------------------------------------------
__global__ __launch_bounds__(512, 2) void gemm_i8_kernel(
    const int8_t* __restrict__ Aq,   // [T][K]
    const int8_t* __restrict__ Bq,   // [N][K]
    const float* __restrict__ scale_x, const float* __restrict__ scale_w,
    const float* __restrict__ bias, float* __restrict__ out)
{
    __shared__ __align__(16) int8_t lds[131072];
    // A: buf*16384 (256 rows x 64B), bufs 0..3 in [0,64K)
    // B: 65536 + buf*16384              in [64K,128K)

    const int tid  = threadIdx.x;
    const int lane = tid & 63;
    const int wid  = tid >> 6;
    const int wmp  = wid >> 2;
    const int wnp  = wid & 3;
    const int l15  = lane & 15, l16 = lane >> 4;

    const int swz  = (blockIdx.x & 7) * 32 + (blockIdx.x >> 3);
    const int row0 = (swz >> 4) * 256;
    const int col0 = (swz & 15) * 256;

    const int srow = wid * 16 + (lane >> 2);
    const int scol = ((lane & 3) ^ ((lane >> 3) & 3)) * 16;
    const int8_t* const A0g = Aq + (size_t)(row0 + srow) * KDIM + scol;
    const int8_t* const B0g = Bq + (size_t)(col0 + srow) * KDIM + scol;
    int8_t* const ldsw = lds + wid * 1024;

#define STAGE_A(db, h, kt) \
    __builtin_amdgcn_global_load_lds( \
        (const __attribute__((address_space(1))) void*)(A0g + (size_t)(h) * 128 * KDIM + (kt) * 64), \
        (__attribute__((address_space(3))) void*)(ldsw + (db) * 16384 + (h) * 8192), 16, 0, 0)
#define STAGE_B(db, h, kt) \
    __builtin_amdgcn_global_load_lds( \
        (const __attribute__((address_space(1))) void*)(B0g + (size_t)(h) * 128 * KDIM + (kt) * 64), \
        (__attribute__((address_space(3))) void*)(ldsw + 65536 + (db) * 16384 + (h) * 8192), 16, 0, 0)

    const int rslot = (l16 ^ ((lane >> 1) & 3)) * 16;
    const int aoff = wmp * 8192 + l15 * 64 + rslot;
    const int boff = (wnp >> 1) * 8192 + (wnp & 1) * 4096 + l15 * 64 + rslot;

    // register sets: two cross-tile prefetch sets (a/b) + shared JIT A-half1
    i32x4 A0a[4], Ba[4], A0b[4], Bb[4], Ar1[4];
    i32x4 acc[8][4];
    #pragma unroll
    for (int m = 0; m < 8; ++m)
        #pragma unroll
        for (int n = 0; n < 4; ++n) acc[m][n] = (i32x4){0, 0, 0, 0};

#define LDA_Q(db, qm, R) { const int8_t* p = lds + (db) * 16384 + aoff + (qm) * 4096; \
    R[0] = *(const i32x4*)(p);        R[1] = *(const i32x4*)(p + 1024); \
    R[2] = *(const i32x4*)(p + 2048); R[3] = *(const i32x4*)(p + 3072); }
#define LDB_ALL(db, R) { const int8_t* p = lds + 65536 + (db) * 16384 + boff; \
    R[0] = *(const i32x4*)(p);        R[1] = *(const i32x4*)(p + 1024); \
    R[2] = *(const i32x4*)(p + 2048); R[3] = *(const i32x4*)(p + 3072); }
// MFMA row i: A-fragment AR[ai] against 4 B-fragments of BR
#define MR(i, AR, ai, BR) { \
    acc[i][0] = __builtin_amdgcn_mfma_i32_16x16x64_i8(AR[ai], BR[0], acc[i][0], 0, 0, 0); \
    acc[i][1] = __builtin_amdgcn_mfma_i32_16x16x64_i8(AR[ai], BR[1], acc[i][1], 0, 0, 0); \
    acc[i][2] = __builtin_amdgcn_mfma_i32_16x16x64_i8(AR[ai], BR[2], acc[i][2], 0, 0, 0); \
    acc[i][3] = __builtin_amdgcn_mfma_i32_16x16x64_i8(AR[ai], BR[3], acc[i][3], 0, 0, 0); }

#define BAR   __builtin_amdgcn_s_barrier()
#define VMCNT8 asm volatile("s_waitcnt vmcnt(8)" ::: "memory")
#define VMCNT0 asm volatile("s_waitcnt vmcnt(0)" ::: "memory")
#define PRIO1 __builtin_amdgcn_s_setprio(1)
#define PRIO0 __builtin_amdgcn_s_setprio(0)

    // interval for tile t: CUR set holds t's B + A-half0 (prefetched last
    // interval); stages t+3; JIT-reads A-half1 under rows 0-3; publishes
    // t+1 mid-interval; prefetches t+1 into NXT under rows 4-7.
#define INTERVAL(rb, sb, u, CA0, CB, NA0, NB, nb) { \
    STAGE_A(sb, 0, u); STAGE_A(sb, 1, u); STAGE_B(sb, 0, u); STAGE_B(sb, 1, u); \
    PRIO1; MR(0, CA0, 0, CB); MR(1, CA0, 1, CB); PRIO0; \
    LDA_Q(rb, 1, Ar1); \
    PRIO1; MR(2, CA0, 2, CB); MR(3, CA0, 3, CB); PRIO0; \
    VMCNT8; BAR; \
    LDB_ALL(nb, NB); LDA_Q(nb, 0, NA0); \
    PRIO1; MR(4, Ar1, 0, CB); MR(5, Ar1, 1, CB); \
           MR(6, Ar1, 2, CB); MR(7, Ar1, 3, CB); PRIO0; }

    // prologue: stage tiles 0,1,2; vmcnt(8) -> tile 0 complete; reads(0).
    STAGE_A(0, 0, 0); STAGE_A(0, 1, 0); STAGE_B(0, 0, 0); STAGE_B(0, 1, 0);
    STAGE_A(1, 0, 1); STAGE_A(1, 1, 1); STAGE_B(1, 0, 1); STAGE_B(1, 1, 1);
    STAGE_A(2, 0, 2); STAGE_A(2, 1, 2); STAGE_B(2, 0, 2); STAGE_B(2, 1, 2);
    VMCNT8;
    BAR;
    LDB_ALL(0, Ba); LDA_Q(0, 0, A0a);

    for (int k = 0; k < 16; ++k) {        // 4 tiles per iteration
        const int t0 = 4 * k;
        const int u0 = (t0 + 3 > 63) ? 63 : t0 + 3;
        const int u1 = (t0 + 4 > 63) ? 63 : t0 + 4;
        const int u2 = (t0 + 5 > 63) ? 63 : t0 + 5;
        const int u3 = (t0 + 6 > 63) ? 63 : t0 + 6;
        INTERVAL(0, 3, u0, A0a, Ba, A0b, Bb, 1);
        INTERVAL(1, 0, u1, A0b, Bb, A0a, Ba, 2);
        INTERVAL(2, 1, u2, A0a, Ba, A0b, Bb, 3);
        INTERVAL(3, 2, u3, A0b, Bb, A0a, Ba, 0);
    }
    VMCNT0;   // drain tail dummy stages

    // epilogue: C/D layout col = lane&15, row = (lane>>4)*4 + reg
    const int orow0 = row0 + wmp * 128;
    const int ocol0 = col0 + wnp * 64;
    #pragma unroll
    for (int fn = 0; fn < 4; ++fn) {
        const int col = ocol0 + fn * 16 + l15;
        const float sw = scale_w[col];
        const float bv = bias[col];
        #pragma unroll
        for (int fm = 0; fm < 8; ++fm) {
            #pragma unroll
            for (int j = 0; j < 4; ++j) {
                const int row = orow0 + fm * 16 + l16 * 4 + j;
                out[(size_t)row * NDIM + col] =
                    (float)acc[fm][fn][j] * scale_x[row] * sw + bv;
            }
        }
    }
#undef STAGE_A
#undef STAGE_B
#undef LDA_Q
#undef LDB_ALL
#undef MR
#undef INTERVAL
#undef BAR
#undef VMCNT8
#undef VMCNT0
#undef PRIO1
#undef PRIO0
}

// ---------------------------------------------------------------------------
extern "C" void kernel_launch(void* const* d_in, const int* in_sizes, int n_in,
                              void* d_out, int out_size, void* d_ws, size_t ws_size,
                              hipStream_t stream)
{
    const float* x        = (const float*)d_in[0];
    const int*   Wq       = (const int*)d_in[1];
    const float* scale    = (const float*)d_in[2];
    const float* zp       = (const float*)d_in[3];
    const float* svd_up   = (const float*)d_in[4];
    const float* svd_down = (const float*)d_in[5];
    const float* bias     = (const float*)d_in[6];
    float* out = (float*)d_out;

    // ws: xq 16MB | wq 16MB | scale_x 16KB | scale_w 16KB | upb 1MB | dnt 1MB
    int8_t* xq = (int8_t*)d_ws;
    int8_t* wq = (int8_t*)d_ws + ((size_t)16 << 20);
    float* scale_x = (float*)((char*)d_ws + ((size_t)32 << 20));
    float* scale_w = scale_x + TDIM;
    unsigned short* upb = (unsigned short*)(scale_w + NDIM);
    unsigned short* dnt = upb + (size_t)NDIM * RANK;

    prep_kernel<<<4096 + 384, 256, 0, stream>>>(x, xq, scale_x,
                                                svd_up, svd_down, upb, dnt);
    fused_w_kernel<<<NDIM / 16, 512, 0, stream>>>(Wq, scale, zp, upb, dnt,
                                                  wq, scale_w);
    gemm_i8_kernel<<<(TDIM / 256) * (NDIM / 256), 512, 0, stream>>>(
        xq, wq, scale_x, scale_w, bias, out);
}

// Round 11
// 132.514 us; speedup vs baseline: 1.0185x; 1.0092x over previous
//
#include <hip/hip_runtime.h>
#include <stdint.h>

#define TDIM 4096   // tokens = 2*2048
#define KDIM 4096   // IN_F
#define NDIM 4096   // OUT_F
#define RANK 128
#define NG   32

typedef __attribute__((ext_vector_type(4))) int   i32x4;
typedef __attribute__((ext_vector_type(4))) float f32x4;
typedef __attribute__((ext_vector_type(8))) short short8;
typedef __attribute__((ext_vector_type(8))) unsigned short u16x8;
typedef __attribute__((ext_vector_type(8))) char c8;

__device__ inline unsigned short f2bf(float f) {   // f32 -> bf16 RNE
    union { float f; unsigned u; } v; v.f = f;
    const unsigned r = v.u + 0x7FFF + ((v.u >> 16) & 1);
    return (unsigned short)(r >> 16);
}
__device__ inline float bf2f(unsigned short h) {
    union { unsigned u; float f; } v; v.u = (unsigned)h << 16;
    return v.f;
}

// ---------------------------------------------------------------------------
// Kernel 1 (merged): blocks 0..4095 = per-token activation quant;
// blocks 4096..4479 = svd bf16 conversion.
// ---------------------------------------------------------------------------
__global__ __launch_bounds__(256) void prep_kernel(
    const float* __restrict__ x, int8_t* __restrict__ xq,
    float* __restrict__ scale_x,
    const float* __restrict__ svd_up, const float* __restrict__ svd_down,
    unsigned short* __restrict__ upb, unsigned short* __restrict__ dnt)
{
    if (blockIdx.x < 4096) {
        const int row = blockIdx.x;
        const float4* xr = (const float4*)(x + (size_t)row * KDIM);
        __shared__ float4 buf[1024];
        __shared__ float wred[4];

        float m = 0.f;
        #pragma unroll
        for (int j = 0; j < 4; ++j) {
            const float4 v = xr[threadIdx.x + j * 256];
            buf[threadIdx.x + j * 256] = v;
            m = fmaxf(m, fmaxf(fmaxf(fabsf(v.x), fabsf(v.y)),
                               fmaxf(fabsf(v.z), fabsf(v.w))));
        }
        #pragma unroll
        for (int off = 32; off > 0; off >>= 1)
            m = fmaxf(m, __shfl_xor(m, off, 64));
        if ((threadIdx.x & 63) == 0) wred[threadIdx.x >> 6] = m;
        __syncthreads();
        const float mt = fmaxf(fmaxf(wred[0], wred[1]), fmaxf(wred[2], wred[3]));
        const float sx = mt / 127.0f;
        if (threadIdx.x == 0) scale_x[row] = sx;

        char4* xo = (char4*)(xq + (size_t)row * KDIM);
        #pragma unroll
        for (int j = 0; j < 4; ++j) {
            const float4 v = buf[threadIdx.x + j * 256];
            char4 q;
            q.x = (char)fminf(fmaxf(rintf(v.x / sx), -128.f), 127.f);
            q.y = (char)fminf(fmaxf(rintf(v.y / sx), -128.f), 127.f);
            q.z = (char)fminf(fmaxf(rintf(v.z / sx), -128.f), 127.f);
            q.w = (char)fminf(fmaxf(rintf(v.w / sx), -128.f), 127.f);
            xo[threadIdx.x + j * 256] = q;
        }
    } else {
        const int b = blockIdx.x - 4096;
        if (b < 256) {
            const int t = b * 256 + threadIdx.x;
            const int i  = t >> 4;
            const int k0 = (t & 15) * 8;
            u16x8 v;
            #pragma unroll
            for (int j = 0; j < 8; ++j)
                v[j] = f2bf(svd_down[(size_t)(k0 + j) * KDIM + i]);
            *(u16x8*)(dnt + (size_t)i * RANK + k0) = v;
        } else {
            const int t = (b - 256) * 256 + threadIdx.x;
            const float4* src = (const float4*)svd_up + (size_t)t * 4;
            #pragma unroll
            for (int h = 0; h < 2; ++h) {
                const float4 a = src[h * 2], c = src[h * 2 + 1];
                u16x8 v;
                v[0] = f2bf(a.x); v[1] = f2bf(a.y); v[2] = f2bf(a.z); v[3] = f2bf(a.w);
                v[4] = f2bf(c.x); v[5] = f2bf(c.y); v[6] = f2bf(c.z); v[7] = f2bf(c.w);
                *(u16x8*)(upb + (size_t)t * 16 + h * 8) = v;
            }
        }
    }
}

// ---------------------------------------------------------------------------
// Kernel 2 (FUSED, unchanged): dequant + SVD corr + row max + quantize.
// ---------------------------------------------------------------------------
__global__ __launch_bounds__(512) void fused_w_kernel(
    const int* __restrict__ Wq, const float* __restrict__ scale,
    const float* __restrict__ zp,
    const unsigned short* __restrict__ upb,   // [4096][128] bf16
    const unsigned short* __restrict__ dnt,   // [4096][128] bf16 (down^T)
    int8_t* __restrict__ wq, float* __restrict__ scale_w)
{
    __shared__ unsigned short wfls[16 * 4096];   // 128 KB
    __shared__ float red[16][8];
    __shared__ float swls[16];

    const int tid  = threadIdx.x;
    const int lane = tid & 63, wid = tid >> 6;   // 8 waves
    const int l15  = lane & 15, l16 = lane >> 4;
    const int o0   = blockIdx.x * 16;

    short8 af[4];
    #pragma unroll
    for (int kk = 0; kk < 4; ++kk)
        af[kk] = *(const short8*)(upb + (size_t)(o0 + l15) * RANK + kk * 32 + l16 * 8);

    const int swz = l16 << 4;
    unsigned umax[4] = {0u, 0u, 0u, 0u};

    for (int c = 0; c < 4; ++c) {
        const int cb = wid * 512 + c * 128;
        const int g  = cb >> 7;

        f32x4 acc[8];
        #pragma unroll
        for (int t = 0; t < 8; ++t) acc[t] = (f32x4){0.f, 0.f, 0.f, 0.f};
        #pragma unroll
        for (int t = 0; t < 8; ++t)
            #pragma unroll
            for (int kk = 0; kk < 4; ++kk) {
                const short8 bfr = *(const short8*)(dnt +
                    (size_t)(cb + t * 16 + l15) * RANK + kk * 32 + l16 * 8);
                acc[t] = __builtin_amdgcn_mfma_f32_16x16x32_bf16(
                             af[kk], bfr, acc[t], 0, 0, 0);
            }

        float s[4], z[4];
        #pragma unroll
        for (int j = 0; j < 4; ++j) {
            const int row = o0 + l16 * 4 + j;
            s[j] = scale[row * NG + g];
            z[j] = zp[row * NG + g];
        }

        #pragma unroll
        for (int t = 0; t < 8; ++t) {
            const int col = cb + t * 16 + l15;
            #pragma unroll
            for (int j = 0; j < 4; ++j) {
                const int r = l16 * 4 + j;
                const float q  = (float)Wq[(size_t)(o0 + r) * KDIM + col];
                const float wf = (q - z[j]) * s[j] + acc[t][j];
                const unsigned short h = f2bf(wf);
                wfls[r * 4096 + (col ^ swz)] = h;
                const unsigned a = h & 0x7FFFu;
                umax[j] = (a > umax[j]) ? a : umax[j];
            }
        }
    }

    #pragma unroll
    for (int j = 0; j < 4; ++j) {
        unsigned v = umax[j];
        v = max(v, (unsigned)__shfl_xor((int)v, 1, 64));
        v = max(v, (unsigned)__shfl_xor((int)v, 2, 64));
        v = max(v, (unsigned)__shfl_xor((int)v, 4, 64));
        v = max(v, (unsigned)__shfl_xor((int)v, 8, 64));
        if (l15 == 0) red[l16 * 4 + j][wid] = bf2f((unsigned short)v);
    }
    __syncthreads();
    if (tid < 16) {
        float m = 0.f;
        #pragma unroll
        for (int w = 0; w < 8; ++w) m = fmaxf(m, red[tid][w]);
        const float sw = m / 127.0f;
        swls[tid] = sw;
        scale_w[o0 + tid] = sw;
    }
    __syncthreads();

    const int r  = tid >> 5;
    const int ml = tid & 31;
    const float sw = swls[r];
    const int rsw = ((r >> 2) & 3) << 4;
    int8_t* wrow = wq + (size_t)(o0 + r) * KDIM;
    #pragma unroll
    for (int k = 0; k < 16; ++k) {
        const int c0 = k * 256 + ml * 8;
        const u16x8 h = *(const u16x8*)(wfls + r * 4096 + (c0 ^ rsw));
        c8 qv;
        #pragma unroll
        for (int e = 0; e < 8; ++e) {
            float f = bf2f((unsigned short)h[e]);
            qv[e] = (char)fminf(fmaxf(rintf(f / sw), -128.f), 127.f);
        }
        *(c8*)(wrow + c0) = qv;
    }
}

// ---------------------------------------------------------------------------
// Kernel 4: int8 GEMM 256x256, BK=64, 4-deep rotation — R10: UNIFORM
// DS/MFMA interleave pinned with sched_group_barrier.
// Accounting (R5-R9, all ~2700cyc/tile): MFMA pipe ~1306 cyc/SIMD + LDS pipe
// ~1280 cyc/CU = sum, not max -> the pipes never overlap. Cause: barrier-
// locked waves all execute [read-batch, MFMA-batch] in the same window
// (macro-phases). Fix: one interval per tile with the 12 ds_reads spread
// uniformly through the 32 MFMAs (4 reads per 8 MFMAs), enforced via T19
// sched_group_barrier; at any instant the wave mix feeds both pipes.
// Interval t: [vmcnt(4); BAR; stage t+3; {mix}]. Safety (re-derived):
//  - stages after BAR: buf (t+3)&3's last reads were mix(t-1) -> sealed by
//    this BAR (old pre-BAR stage order was racy).
//  - vmcnt(4): outstanding {t+1,t+2}=8 -> drains t+1; BAR publishes it;
//    mix(t) reads buf t (A1 JIT) + buf t+1 (B/A0 prefetch -> regs).
//  - prefetch regs consumed in mix(t+1) (lgkm before first MFMA use),
//    buf t+1 re-staged in interval t+2 -> one-interval slack. Safe.
//  - tail: u clamped to 63 (dummy stages, rotation bufs); final interval
//    prefetch reads buf0 garbage into dead regs. vmcnt(0) before epilogue.
// ---------------------------------------------------------------------------
__global__ __launch_bounds__(512, 2) void gemm_i8_kernel(
    const int8_t* __restrict__ Aq,   // [T][K]
    const int8_t* __restrict__ Bq,   // [N][K]
    const float* __restrict__ scale_x, const float* __restrict__ scale_w,
    const float* __restrict__ bias, float* __restrict__ out)
{
    __shared__ __align__(16) int8_t lds[131072];
    // A: buf*16384, bufs 0..3 in [0,64K); B: 65536 + buf*16384 in [64K,128K)

    const int tid  = threadIdx.x;
    const int lane = tid & 63;
    const int wid  = tid >> 6;
    const int wmp  = wid >> 2;
    const int wnp  = wid & 3;
    const int l15  = lane & 15, l16 = lane >> 4;

    const int swz  = (blockIdx.x & 7) * 32 + (blockIdx.x >> 3);
    const int row0 = (swz >> 4) * 256;
    const int col0 = (swz & 15) * 256;

    const int srow = wid * 16 + (lane >> 2);
    const int scol = ((lane & 3) ^ ((lane >> 3) & 3)) * 16;
    const int8_t* const A0g = Aq + (size_t)(row0 + srow) * KDIM + scol;
    const int8_t* const B0g = Bq + (size_t)(col0 + srow) * KDIM + scol;
    int8_t* const ldsw = lds + wid * 1024;

#define STAGE_A(db, h, kt) \
    __builtin_amdgcn_global_load_lds( \
        (const __attribute__((address_space(1))) void*)(A0g + (size_t)(h) * 128 * KDIM + (kt) * 64), \
        (__attribute__((address_space(3))) void*)(ldsw + (db) * 16384 + (h) * 8192), 16, 0, 0)
#define STAGE_B(db, h, kt) \
    __builtin_amdgcn_global_load_lds( \
        (const __attribute__((address_space(1))) void*)(B0g + (size_t)(h) * 128 * KDIM + (kt) * 64), \
        (__attribute__((address_space(3))) void*)(ldsw + 65536 + (db) * 16384 + (h) * 8192), 16, 0, 0)

    const int rslot = (l16 ^ ((lane >> 1) & 3)) * 16;
    const int aoff = wmp * 8192 + l15 * 64 + rslot;
    const int boff = (wnp >> 1) * 8192 + (wnp & 1) * 4096 + l15 * 64 + rslot;

    i32x4 A0a[4], Ba[4], A0b[4], Bb[4], Ar1[4];
    i32x4 acc[8][4];
    #pragma unroll
    for (int m = 0; m < 8; ++m)
        #pragma unroll
        for (int n = 0; n < 4; ++n) acc[m][n] = (i32x4){0, 0, 0, 0};

#define LDA_Q(db, qm, R) { const int8_t* p = lds + (db) * 16384 + aoff + (qm) * 4096; \
    R[0] = *(const i32x4*)(p);        R[1] = *(const i32x4*)(p + 1024); \
    R[2] = *(const i32x4*)(p + 2048); R[3] = *(const i32x4*)(p + 3072); }
#define LDB_ALL(db, R) { const int8_t* p = lds + 65536 + (db) * 16384 + boff; \
    R[0] = *(const i32x4*)(p);        R[1] = *(const i32x4*)(p + 1024); \
    R[2] = *(const i32x4*)(p + 2048); R[3] = *(const i32x4*)(p + 3072); }
#define MR(i, AR, ai, BR) { \
    acc[i][0] = __builtin_amdgcn_mfma_i32_16x16x64_i8(AR[ai], BR[0], acc[i][0], 0, 0, 0); \
    acc[i][1] = __builtin_amdgcn_mfma_i32_16x16x64_i8(AR[ai], BR[1], acc[i][1], 0, 0, 0); \
    acc[i][2] = __builtin_amdgcn_mfma_i32_16x16x64_i8(AR[ai], BR[2], acc[i][2], 0, 0, 0); \
    acc[i][3] = __builtin_amdgcn_mfma_i32_16x16x64_i8(AR[ai], BR[3], acc[i][3], 0, 0, 0); }

#define BAR   __builtin_amdgcn_s_barrier()
#define VMCNT4 asm volatile("s_waitcnt vmcnt(4)" ::: "memory")
#define VMCNT8 asm volatile("s_waitcnt vmcnt(8)" ::: "memory")
#define VMCNT0 asm volatile("s_waitcnt vmcnt(0)" ::: "memory")
#define PRIO1 __builtin_amdgcn_s_setprio(1)
#define PRIO0 __builtin_amdgcn_s_setprio(0)
#define SGB(m, n) __builtin_amdgcn_sched_group_barrier(m, n, 0)
// pin: 4 stage-VMEM, then (4 DS / 8 MFMA) x2, 4 DS, 16 MFMA
#define SGB_PIN { SGB(0x20, 4); SGB(0x100, 4); SGB(0x8, 8); \
                  SGB(0x100, 4); SGB(0x8, 8); SGB(0x100, 4); SGB(0x8, 16); }

#define INTERVAL(rb, sb, u, CA0, CB, NA0, NB, nb) { \
    VMCNT4; BAR; \
    STAGE_A(sb, 0, u); STAGE_A(sb, 1, u); STAGE_B(sb, 0, u); STAGE_B(sb, 1, u); \
    LDA_Q(rb, 1, Ar1); \
    PRIO1; MR(0, CA0, 0, CB); MR(1, CA0, 1, CB); PRIO0; \
    LDB_ALL(nb, NB); \
    PRIO1; MR(2, CA0, 2, CB); MR(3, CA0, 3, CB); PRIO0; \
    LDA_Q(nb, 0, NA0); \
    PRIO1; MR(4, Ar1, 0, CB); MR(5, Ar1, 1, CB); \
           MR(6, Ar1, 2, CB); MR(7, Ar1, 3, CB); PRIO0; \
    SGB_PIN; }

    // prologue: stage tiles 0,1,2 (12 loads); drain tile0; read its B/A0.
    STAGE_A(0, 0, 0); STAGE_A(0, 1, 0); STAGE_B(0, 0, 0); STAGE_B(0, 1, 0);
    STAGE_A(1, 0, 1); STAGE_A(1, 1, 1); STAGE_B(1, 0, 1); STAGE_B(1, 1, 1);
    STAGE_A(2, 0, 2); STAGE_A(2, 1, 2); STAGE_B(2, 0, 2); STAGE_B(2, 1, 2);
    VMCNT8;
    BAR;
    LDB_ALL(0, Ba); LDA_Q(0, 0, A0a);

    for (int k = 0; k < 16; ++k) {        // 4 tiles per iteration
        const int t0 = 4 * k;
        const int u0 = (t0 + 3 > 63) ? 63 : t0 + 3;
        const int u1 = (t0 + 4 > 63) ? 63 : t0 + 4;
        const int u2 = (t0 + 5 > 63) ? 63 : t0 + 5;
        const int u3 = (t0 + 6 > 63) ? 63 : t0 + 6;
        INTERVAL(0, 3, u0, A0a, Ba, A0b, Bb, 1);
        INTERVAL(1, 0, u1, A0b, Bb, A0a, Ba, 2);
        INTERVAL(2, 1, u2, A0a, Ba, A0b, Bb, 3);
        INTERVAL(3, 2, u3, A0b, Bb, A0a, Ba, 0);
    }
    VMCNT0;   // drain tail dummy stages

    // epilogue: C/D layout col = lane&15, row = (lane>>4)*4 + reg
    const int orow0 = row0 + wmp * 128;
    const int ocol0 = col0 + wnp * 64;
    #pragma unroll
    for (int fn = 0; fn < 4; ++fn) {
        const int col = ocol0 + fn * 16 + l15;
        const float sw = scale_w[col];
        const float bv = bias[col];
        #pragma unroll
        for (int fm = 0; fm < 8; ++fm) {
            #pragma unroll
            for (int j = 0; j < 4; ++j) {
                const int row = orow0 + fm * 16 + l16 * 4 + j;
                out[(size_t)row * NDIM + col] =
                    (float)acc[fm][fn][j] * scale_x[row] * sw + bv;
            }
        }
    }
#undef STAGE_A
#undef STAGE_B
#undef LDA_Q
#undef LDB_ALL
#undef MR
#undef INTERVAL
#undef SGB
#undef SGB_PIN
#undef BAR
#undef VMCNT4
#undef VMCNT8
#undef VMCNT0
#undef PRIO1
#undef PRIO0
}

// ---------------------------------------------------------------------------
extern "C" void kernel_launch(void* const* d_in, const int* in_sizes, int n_in,
                              void* d_out, int out_size, void* d_ws, size_t ws_size,
                              hipStream_t stream)
{
    const float* x        = (const float*)d_in[0];
    const int*   Wq       = (const int*)d_in[1];
    const float* scale    = (const float*)d_in[2];
    const float* zp       = (const float*)d_in[3];
    const float* svd_up   = (const float*)d_in[4];
    const float* svd_down = (const float*)d_in[5];
    const float* bias     = (const float*)d_in[6];
    float* out = (float*)d_out;

    // ws: xq 16MB | wq 16MB | scale_x 16KB | scale_w 16KB | upb 1MB | dnt 1MB
    int8_t* xq = (int8_t*)d_ws;
    int8_t* wq = (int8_t*)d_ws + ((size_t)16 << 20);
    float* scale_x = (float*)((char*)d_ws + ((size_t)32 << 20));
    float* scale_w = scale_x + TDIM;
    unsigned short* upb = (unsigned short*)(scale_w + NDIM);
    unsigned short* dnt = upb + (size_t)NDIM * RANK;

    prep_kernel<<<4096 + 384, 256, 0, stream>>>(x, xq, scale_x,
                                                svd_up, svd_down, upb, dnt);
    fused_w_kernel<<<NDIM / 16, 512, 0, stream>>>(Wq, scale, zp, upb, dnt,
                                                  wq, scale_w);
    gemm_i8_kernel<<<(TDIM / 256) * (NDIM / 256), 512, 0, stream>>>(
        xq, wq, scale_x, scale_w, bias, out);
}